// Round 1
// baseline (198.130 us; speedup 1.0000x reference)
//
#include <hip/hip_runtime.h>
#include <hip/hip_bf16.h>

// HyConv round 9: (a) gemm LDS 48->32KB (theta in 4x32-row chunks) so the fused
// build/gemm kernel gets 5 blocks/CU instead of 3 — build path is latency-bound on
// random atomics and needs the waves; (b) non-temporal x loads / xt stores in gemm to
// stop streaming traffic from cycling the XCD-local scatter lines out of L2
// (WRITE_SIZE 70MB vs ~33MB unique dirty); (c) XCD batch-affinity swizzle in the
// phase kernels: batch b -> XCD pair {2b,2b+1}, so each XCD's 2.56MB gather slice is
// L2-resident (~16x reuse) instead of 10.24MB spread over all XCDs; streaming outputs
// (x_edge, out) stored non-temporally to protect the gather set.
// memset(ctr) -> build_gemm (1 gemm : 2 build) -> phase1_pull -> phase2_pull

#define BB 4
#define NN 10000
#define MM 10000
#define EE 160000
#define CC 128
#define BM (BB * MM)   // 40000 hyperedge buckets
#define BN (BB * NN)   // 40000 node buckets
#define NCOPY 8
#define CAPX 16        // per-copy bucket capacity; per-copy deg ~ Poisson(2), P[>=17]~5e-11

typedef unsigned short u16;
using bf16 = __hip_bfloat16;
using bf162 = __hip_bfloat162;
typedef float f4 __attribute__((ext_vector_type(4)));
typedef float f2 __attribute__((ext_vector_type(2)));

// ---------------- fused: gemm (bi%3==0) || build (bi%3!=0) ----------------
// grid = 3750: 1250 gemm blocks (32 rows each), 2500 build blocks (640k edges).
__global__ __launch_bounds__(256) void build_gemm_k(const int* __restrict__ H,
                                                    int* __restrict__ ctr,
                                                    u16* __restrict__ srcA,
                                                    u16* __restrict__ srcB,
                                                    const float* __restrict__ x,
                                                    const float* __restrict__ theta,
                                                    bf16* __restrict__ xt) {
    __shared__ float sTh[32 * 128];  // 16 KB (theta chunk: 32 rows)
    __shared__ float sX[32 * 128];   // 16 KB  -> 32KB total = 5 blocks/CU
    const int bi = blockIdx.x;

    if (bi % 3 != 0) {
        // ---- build: one thread per edge, XCD-local copy = bi & 7 ----
        const int j = bi - bi / 3 - 1;               // 0..2499 among build blocks
        const int g = j * 256 + threadIdx.x;         // 0..639,999
        if (g >= BB * EE) return;
        const int cp = bi & 7;
        const int b = g / EE, e = g - b * EE;
        const int nd = H[b * 2 * EE + e];
        const int he = H[b * 2 * EE + EE + e];
        const int bktA = b * MM + he;
        const int s = atomicAdd(&ctr[cp * (BM + BN) + bktA], 1);
        if (s < CAPX) srcA[((size_t)cp * BM + bktA) * CAPX + s] = (u16)nd;
        const int bktB = b * NN + nd;
        const int q = atomicAdd(&ctr[cp * (BM + BN) + BM + bktB], 1);
        if (q < CAPX) srcB[((size_t)cp * BN + bktB) * CAPX + q] = (u16)he;
        return;
    }

    // ---- gemm: 32 rows x 128 cols per block; thread = 8 rows x 2 cols ----
    const int tid = threadIdx.x;
    const int row0 = (bi / 3) * 32;  // 0..1249 -> rows 0..39968
    {
        // streaming read, never reused by this or any later kernel from L2: NT
        const f4* src = (const f4*)&x[row0 * 128];  // 1024 float4
        f4* dst = (f4*)sX;
#pragma unroll
        for (int i = 0; i < 4; ++i)
            dst[tid + 256 * i] = __builtin_nontemporal_load(src + tid + 256 * i);
    }
    const int cg2 = (tid & 63) * 2;  // column pair base (0..126)
    const int rg = tid >> 6;         // row group 0..3
    float ax[8], ay[8];
#pragma unroll
    for (int r = 0; r < 8; ++r) { ax[r] = 0.f; ay[r] = 0.f; }

    for (int q = 0; q < 4; ++q) {
        __syncthreads();
        {
            const f4* src = (const f4*)&theta[q * 32 * 128];
            f4* dst = (f4*)sTh;
#pragma unroll
            for (int i = 0; i < 4; ++i) dst[tid + 256 * i] = src[tid + 256 * i];
        }
        __syncthreads();
#pragma unroll
        for (int k4 = 0; k4 < 8; ++k4) {
            const int kk = 4 * k4;
            const float2 t0 = *(const float2*)&sTh[(kk + 0) * 128 + cg2];
            const float2 t1 = *(const float2*)&sTh[(kk + 1) * 128 + cg2];
            const float2 t2 = *(const float2*)&sTh[(kk + 2) * 128 + cg2];
            const float2 t3 = *(const float2*)&sTh[(kk + 3) * 128 + cg2];
#pragma unroll
            for (int r = 0; r < 8; ++r) {
                const float4 xv =
                    *(const float4*)&sX[(rg * 8 + r) * 128 + q * 32 + kk];
                ax[r] = fmaf(xv.x, t0.x, ax[r]); ay[r] = fmaf(xv.x, t0.y, ay[r]);
                ax[r] = fmaf(xv.y, t1.x, ax[r]); ay[r] = fmaf(xv.y, t1.y, ay[r]);
                ax[r] = fmaf(xv.z, t2.x, ax[r]); ay[r] = fmaf(xv.z, t2.y, ay[r]);
                ax[r] = fmaf(xv.w, t3.x, ax[r]); ay[r] = fmaf(xv.w, t3.y, ay[r]);
            }
        }
    }
#pragma unroll
    for (int r = 0; r < 8; ++r) {
        bf162 h;
        h.x = __float2bfloat16(ax[r]);
        h.y = __float2bfloat16(ay[r]);
        // xt is consumed next-kernel (cross-XCD) — don't let it evict scatter lines
        __builtin_nontemporal_store(
            *(unsigned*)&h,
            (unsigned*)&xt[(size_t)(row0 + rg * 8 + r) * 128 + cg2]);
    }
}

// ---------------- gather helper: accumulate one bf16 row (2 channels/lane) ----------
__device__ __forceinline__ void gacc(const bf16* __restrict__ base, int idx, int lane,
                                     float& sx, float& sy) {
    const unsigned raw = *(const unsigned*)(base + (size_t)idx * CC + lane * 2);
    sx += __uint_as_float(raw << 16);
    sy += __uint_as_float(raw & 0xffff0000u);
}

// ---------------- in-wave merge of 8 copy-lists into LDS, then flat gather ----------
// side_off: 0 for A-side counters, BM for B-side. Bx: BM or BN (copy stride).
// Returns total entry count; flat list left in buf[0..total).
__device__ __forceinline__ int merge_lists(const int* __restrict__ ctr,
                                           const u16* __restrict__ src,
                                           int side_off, int Bx, int wid, int lane,
                                           u16* __restrict__ buf) {
    int cnt = 0;
    if (lane < NCOPY) {
        cnt = ctr[lane * (BM + BN) + side_off + wid];
        cnt = cnt > CAPX ? CAPX : cnt;
    }
    int pre = cnt;  // inclusive prefix over lanes 0..7 (higher lanes: garbage, unused)
#pragma unroll
    for (int d = 1; d < 8; d <<= 1) {
        int o = __shfl_up(pre, d, 64);
        if (lane >= d) pre += o;
    }
    const int base = pre - cnt;
    int total = __shfl(pre, 7, 64);
    total = total > 64 ? 64 : total;
    if (lane < NCOPY && cnt) {
        const u16* lst = src + ((size_t)lane * Bx + wid) * CAPX;
        for (int j = 0; j < cnt; ++j) {
            const int p = base + j;
            if (p < 64) buf[p] = lst[j];
        }
    }
    __syncthreads();  // publish LDS lists (block-wide; all waves reach it)
    return total;
}

// XCD batch-affinity swizzle: default dispatch is round-robin blk->XCD (blk&7).
// Map batch b to XCD pair {2b,2b+1}; jj = block-within-batch (0..2499), bijective.
__device__ __forceinline__ void swz_bucket(int blk, int tid, int& b, int& wid_local4) {
    const int xcd = blk & 7;
    b = xcd >> 1;                                   // batch 0..3
    const int jj = ((blk >> 3) << 1) | (xcd & 1);   // 0..2499
    wid_local4 = jj * 4 + (tid >> 6);               // bucket within batch
}

// ---------------- phase1: x_edge[bkt] = mean over incident nodes of xt ----------------
__global__ __launch_bounds__(256) void phase1_pull(const bf16* __restrict__ xt,
                                                   const int* __restrict__ ctr,
                                                   const u16* __restrict__ srcA,
                                                   bf16* __restrict__ x_edge) {
    __shared__ __align__(16) u16 buf[4 * 64];  // 4 waves x 64 entries
    int b, wl;
    swz_bucket(blockIdx.x, threadIdx.x, b, wl);
    const int wid = b * MM + wl;                    // bucket = b*MM+he
    const int lane = threadIdx.x & 63;
    u16* wbuf = &buf[(threadIdx.x >> 6) * 64];
    const int total = merge_lists(ctr, srcA, 0, BM, wid, lane, wbuf);

    const bf16* base = xt + (size_t)b * NN * CC;    // 2.56MB slice, L2-local to XCD pair
    float sx = 0.f, sy = 0.f;
    int i = 0;
    for (; i + 8 <= total; i += 8) {
        const uint4 pk = *(const uint4*)&wbuf[i];  // LDS broadcast read
        gacc(base, pk.x & 0xffff, lane, sx, sy);
        gacc(base, pk.x >> 16, lane, sx, sy);
        gacc(base, pk.y & 0xffff, lane, sx, sy);
        gacc(base, pk.y >> 16, lane, sx, sy);
        gacc(base, pk.z & 0xffff, lane, sx, sy);
        gacc(base, pk.z >> 16, lane, sx, sy);
        gacc(base, pk.w & 0xffff, lane, sx, sy);
        gacc(base, pk.w >> 16, lane, sx, sy);
    }
    for (; i < total; ++i) gacc(base, wbuf[i], lane, sx, sy);
    const float w = total ? 1.0f / (float)total : 0.f;
    bf162 h;
    h.x = __float2bfloat16(sx * w);
    h.y = __float2bfloat16(sy * w);
    // streaming output, read next-kernel from L3 — keep it out of this XCD's L2
    __builtin_nontemporal_store(*(unsigned*)&h,
                                (unsigned*)&x_edge[(size_t)wid * CC + lane * 2]);
}

// ---------------- phase2: out[bkt] = mean over incident hyperedges + bias ------------
__global__ __launch_bounds__(256) void phase2_pull(const bf16* __restrict__ x_edge,
                                                   const int* __restrict__ ctr,
                                                   const u16* __restrict__ srcB,
                                                   const float* __restrict__ bias,
                                                   float* __restrict__ out) {
    __shared__ __align__(16) u16 buf[4 * 64];
    int b, wl;
    swz_bucket(blockIdx.x, threadIdx.x, b, wl);
    const int wid = b * NN + wl;                    // bucket = b*NN+nd
    const int lane = threadIdx.x & 63;
    u16* wbuf = &buf[(threadIdx.x >> 6) * 64];
    const int total = merge_lists(ctr, srcB, BM, BN, wid, lane, wbuf);

    const bf16* base = x_edge + (size_t)b * MM * CC;  // same XCD pair wrote this slice
    float sx = 0.f, sy = 0.f;
    int i = 0;
    for (; i + 8 <= total; i += 8) {
        const uint4 pk = *(const uint4*)&wbuf[i];
        gacc(base, pk.x & 0xffff, lane, sx, sy);
        gacc(base, pk.x >> 16, lane, sx, sy);
        gacc(base, pk.y & 0xffff, lane, sx, sy);
        gacc(base, pk.y >> 16, lane, sx, sy);
        gacc(base, pk.z & 0xffff, lane, sx, sy);
        gacc(base, pk.z >> 16, lane, sx, sy);
        gacc(base, pk.w & 0xffff, lane, sx, sy);
        gacc(base, pk.w >> 16, lane, sx, sy);
    }
    for (; i < total; ++i) gacc(base, wbuf[i], lane, sx, sy);
    const float w = total ? 1.0f / (float)total : 0.f;
    const float2 bv = *(const float2*)&bias[lane * 2];
    f2 o;
    o.x = sx * w + bv.x;
    o.y = sy * w + bv.y;
    // pure streaming fp32 output (20.5MB) — NT so it can't evict the x_edge gather set
    __builtin_nontemporal_store(o, (f2*)&out[(size_t)wid * CC + lane * 2]);
}

extern "C" void kernel_launch(void* const* d_in, const int* in_sizes, int n_in,
                              void* d_out, int out_size, void* d_ws, size_t ws_size,
                              hipStream_t stream) {
    const float* x = (const float*)d_in[0];
    const int* H = (const int*)d_in[1];
    const float* theta = (const float*)d_in[2];
    const float* bias = (const float*)d_in[3];
    float* out = (float*)d_out;

    // workspace (~43.5 MB): xt(bf16) | x_edge(bf16) | ctr(8 copies) | srcA | srcB
    bf16* xt = (bf16*)d_ws;                                   // 10.24 MB
    bf16* x_edge = xt + (size_t)BB * NN * CC;                 // 10.24 MB
    int* ctr = (int*)(x_edge + (size_t)BB * MM * CC);         // 2.56 MB
    u16* srcA = (u16*)(ctr + NCOPY * (BM + BN));              // 10.24 MB
    u16* srcB = srcA + (size_t)NCOPY * BM * CAPX;             // 10.24 MB

    hipMemsetAsync(ctr, 0, (size_t)NCOPY * (BM + BN) * sizeof(int), stream);

    build_gemm_k<<<3750, 256, 0, stream>>>(H, ctr, srcA, srcB, x, theta, xt);
    phase1_pull<<<BM / 4, 256, 0, stream>>>(xt, ctr, srcA, x_edge);
    phase2_pull<<<BN / 4, 256, 0, stream>>>(x_edge, ctr, srcB, bias, out);
}

// Round 3
// 184.463 us; speedup vs baseline: 1.0741x; 1.0741x over previous
//
#include <hip/hip_runtime.h>
#include <hip/hip_bf16.h>

// HyConv round 10b: same as round 10 (build_gemm reverted to round-8 form; phase
// kernels rebuilt as 4-rows-per-wave-load uint4 gathers + vectorized fragment merge;
// XCD batch-affinity swizzle kept), with the compile fix: __builtin_nontemporal_store
// requires scalar/ext_vector pointers, so the two wide NT stores go through
// ext_vector_type(4) typedefs instead of HIP's uint4/float4 class types.
// memset(ctr) -> build_gemm (1 gemm : 2 build) -> phase1_pull -> phase2_pull

#define BB 4
#define NN 10000
#define MM 10000
#define EE 160000
#define CC 128
#define BM (BB * MM)   // 40000 hyperedge buckets
#define BN (BB * NN)   // 40000 node buckets
#define NCOPY 8
#define CAPX 16        // per-copy bucket capacity; per-copy deg ~ Poisson(2), P[>=17]~5e-11

typedef unsigned short u16;
using bf16 = __hip_bfloat16;
using bf162 = __hip_bfloat162;
typedef unsigned u32x4 __attribute__((ext_vector_type(4)));
typedef float f32x4 __attribute__((ext_vector_type(4)));

// ---------------- fused: gemm (bi%3==0) || build (bi%3!=0) ----------------
// grid = 3750: 1250 gemm blocks (32 rows each), 2500 build blocks (640k edges).
__global__ __launch_bounds__(256) void build_gemm_k(const int* __restrict__ H,
                                                    int* __restrict__ ctr,
                                                    u16* __restrict__ srcA,
                                                    u16* __restrict__ srcB,
                                                    const float* __restrict__ x,
                                                    const float* __restrict__ theta,
                                                    bf16* __restrict__ xt) {
    __shared__ float sTh[64 * 128];  // 32 KB
    __shared__ float sX[32 * 128];   // 16 KB
    const int bi = blockIdx.x;

    if (bi % 3 != 0) {
        // ---- build: one thread per edge, XCD-local copy = bi & 7 ----
        const int j = bi - bi / 3 - 1;               // 0..2499 among build blocks
        const int g = j * 256 + threadIdx.x;         // 0..639,999
        if (g >= BB * EE) return;
        const int cp = bi & 7;
        const int b = g / EE, e = g - b * EE;
        const int nd = H[b * 2 * EE + e];
        const int he = H[b * 2 * EE + EE + e];
        const int bktA = b * MM + he;
        const int s = atomicAdd(&ctr[cp * (BM + BN) + bktA], 1);
        if (s < CAPX) srcA[((size_t)cp * BM + bktA) * CAPX + s] = (u16)nd;
        const int bktB = b * NN + nd;
        const int q = atomicAdd(&ctr[cp * (BM + BN) + BM + bktB], 1);
        if (q < CAPX) srcB[((size_t)cp * BN + bktB) * CAPX + q] = (u16)he;
        return;
    }

    // ---- gemm: 32 rows x 128 cols per block; thread = 8 rows x 2 cols ----
    const int tid = threadIdx.x;
    const int row0 = (bi / 3) * 32;  // 0..1249 -> rows 0..39968
    {
        const float4* src = (const float4*)&x[row0 * 128];  // 1024 float4
        float4* dst = (float4*)sX;
#pragma unroll
        for (int i = 0; i < 4; ++i) dst[tid + 256 * i] = src[tid + 256 * i];
    }
    const int cg2 = (tid & 63) * 2;  // column pair base (0..126)
    const int rg = tid >> 6;         // row group 0..3
    float ax[8], ay[8];
#pragma unroll
    for (int r = 0; r < 8; ++r) { ax[r] = 0.f; ay[r] = 0.f; }

    for (int half = 0; half < 2; ++half) {
        __syncthreads();
        {
            const float4* src = (const float4*)&theta[half * 64 * 128];
            float4* dst = (float4*)sTh;
#pragma unroll
            for (int i = 0; i < 8; ++i) dst[tid + 256 * i] = src[tid + 256 * i];
        }
        __syncthreads();
#pragma unroll
        for (int k4 = 0; k4 < 16; ++k4) {
            const int kk = 4 * k4;
            const float2 t0 = *(const float2*)&sTh[(kk + 0) * 128 + cg2];
            const float2 t1 = *(const float2*)&sTh[(kk + 1) * 128 + cg2];
            const float2 t2 = *(const float2*)&sTh[(kk + 2) * 128 + cg2];
            const float2 t3 = *(const float2*)&sTh[(kk + 3) * 128 + cg2];
#pragma unroll
            for (int r = 0; r < 8; ++r) {
                const float4 xv =
                    *(const float4*)&sX[(rg * 8 + r) * 128 + half * 64 + kk];
                ax[r] = fmaf(xv.x, t0.x, ax[r]); ay[r] = fmaf(xv.x, t0.y, ay[r]);
                ax[r] = fmaf(xv.y, t1.x, ax[r]); ay[r] = fmaf(xv.y, t1.y, ay[r]);
                ax[r] = fmaf(xv.z, t2.x, ax[r]); ay[r] = fmaf(xv.z, t2.y, ay[r]);
                ax[r] = fmaf(xv.w, t3.x, ax[r]); ay[r] = fmaf(xv.w, t3.y, ay[r]);
            }
        }
    }
#pragma unroll
    for (int r = 0; r < 8; ++r) {
        bf162 h;
        h.x = __float2bfloat16(ax[r]);
        h.y = __float2bfloat16(ay[r]);
        *(bf162*)&xt[(size_t)(row0 + rg * 8 + r) * 128 + cg2] = h;
    }
}

// ---------------- bf16-pair helpers ----------------
__device__ __forceinline__ float blo(unsigned w) { return __uint_as_float(w << 16); }
__device__ __forceinline__ float bhi(unsigned w) { return __uint_as_float(w & 0xffff0000u); }
__device__ __forceinline__ unsigned pk2(float a, float b) {
    bf162 h;
    h.x = __float2bfloat16(a);
    h.y = __float2bfloat16(b);
    return *(unsigned*)&h;
}

// accumulate 8 channels from a 16B chunk of one row
__device__ __forceinline__ void acc8(const uint4 pk, float* s) {
    s[0] += blo(pk.x); s[1] += bhi(pk.x);
    s[2] += blo(pk.y); s[3] += bhi(pk.y);
    s[4] += blo(pk.z); s[5] += bhi(pk.z);
    s[6] += blo(pk.w); s[7] += bhi(pk.w);
}

// ---------------- in-wave merge of 8 copy-lists into LDS, then flat gather ----------
// side_off: 0 for A-side counters, BM for B-side. Bx: BM or BN (copy stride).
// Returns total entry count; flat list left in buf[0..total).
// Fragment copy is vectorized: 2 uint4 loads grab the whole 32B fragment (CAPX=16
// u16), then unrolled predicated LDS stores — one round trip instead of a serial
// chain of <=16 scalar u16 global loads.
__device__ __forceinline__ int merge_lists(const int* __restrict__ ctr,
                                           const u16* __restrict__ src,
                                           int side_off, int Bx, int wid, int lane,
                                           u16* __restrict__ buf) {
    int cnt = 0;
    if (lane < NCOPY) {
        cnt = ctr[lane * (BM + BN) + side_off + wid];
        cnt = cnt > CAPX ? CAPX : cnt;
    }
    int pre = cnt;  // inclusive prefix over lanes 0..7 (higher lanes: garbage, unused)
#pragma unroll
    for (int d = 1; d < 8; d <<= 1) {
        int o = __shfl_up(pre, d, 64);
        if (lane >= d) pre += o;
    }
    const int base = pre - cnt;
    int total = __shfl(pre, 7, 64);
    total = total > 64 ? 64 : total;
    if (lane < NCOPY && cnt) {
        const u16* lst = src + ((size_t)lane * Bx + wid) * CAPX;
        const uint4 f0 = *(const uint4*)lst;        // entries 0..7
        const uint4 f1 = *(const uint4*)(lst + 8);  // entries 8..15
        const unsigned wd[8] = {f0.x, f0.y, f0.z, f0.w, f1.x, f1.y, f1.z, f1.w};
#pragma unroll
        for (int j = 0; j < CAPX; ++j) {  // j compile-time -> wd[] stays in regs
            const u16 v = (u16)((j & 1) ? (wd[j >> 1] >> 16) : (wd[j >> 1] & 0xffffu));
            const int p = base + j;
            if (j < cnt && p < 64) buf[p] = v;
        }
    }
    __syncthreads();  // publish LDS lists (block-wide; all waves reach it)
    return total;
}

// XCD batch-affinity swizzle: default dispatch is round-robin blk->XCD (blk&7).
// Map batch b to XCD pair {2b,2b+1}; jj = block-within-batch (0..2499), bijective.
__device__ __forceinline__ void swz_bucket(int blk, int tid, int& b, int& wid_local4) {
    const int xcd = blk & 7;
    b = xcd >> 1;                                   // batch 0..3
    const int jj = ((blk >> 3) << 1) | (xcd & 1);   // 0..2499
    wid_local4 = jj * 4 + (tid >> 6);               // bucket within batch
}

// ---------------- phase1: x_edge[bkt] = mean over incident nodes of xt ----------------
// Gather: lane reads uint4 (16B = 8 channels); 64 lanes cover 4 rows per load.
__global__ __launch_bounds__(256) void phase1_pull(const bf16* __restrict__ xt,
                                                   const int* __restrict__ ctr,
                                                   const u16* __restrict__ srcA,
                                                   bf16* __restrict__ x_edge) {
    __shared__ __align__(16) u16 buf[4 * 64];  // 4 waves x 64 entries
    int b, wl;
    swz_bucket(blockIdx.x, threadIdx.x, b, wl);
    const int wid = b * MM + wl;                    // bucket = b*MM+he
    const int lane = threadIdx.x & 63;
    u16* wbuf = &buf[(threadIdx.x >> 6) * 64];
    const int total = merge_lists(ctr, srcA, 0, BM, wid, lane, wbuf);

    const bf16* base = xt + (size_t)b * NN * CC;    // 2.56MB slice, L2-local to XCD pair
    const int g = lane >> 4;     // row-group 0..3
    const int c16 = lane & 15;   // 16B chunk -> channels c16*8 .. +8
    float s[8];
#pragma unroll
    for (int k = 0; k < 8; ++k) s[k] = 0.f;
    int i = 0;
    for (; i + 4 <= total; i += 4) {
        const int idx = wbuf[i + g];
        const uint4 pk = *(const uint4*)(base + (size_t)idx * CC + c16 * 8);
        acc8(pk, s);
    }
    if (i < total && g < total - i) {  // tail: 1..3 rows, groups >= rem idle
        const int idx = wbuf[i + g];
        const uint4 pk = *(const uint4*)(base + (size_t)idx * CC + c16 * 8);
        acc8(pk, s);
    }
#pragma unroll
    for (int k = 0; k < 8; ++k) {      // sum the 4 row-groups
        s[k] += __shfl_xor(s[k], 16, 64);
        s[k] += __shfl_xor(s[k], 32, 64);
    }
    const float w = total ? 1.0f / (float)total : 0.f;
    if (g == 0) {                       // 16 lanes store 16B each (256B/wave)
        u32x4 o;
        o.x = pk2(s[0] * w, s[1] * w);
        o.y = pk2(s[2] * w, s[3] * w);
        o.z = pk2(s[4] * w, s[5] * w);
        o.w = pk2(s[6] * w, s[7] * w);
        __builtin_nontemporal_store(o, (u32x4*)&x_edge[(size_t)wid * CC + c16 * 8]);
    }
}

// ---------------- phase2: out[bkt] = mean over incident hyperedges + bias ------------
__global__ __launch_bounds__(256) void phase2_pull(const bf16* __restrict__ x_edge,
                                                   const int* __restrict__ ctr,
                                                   const u16* __restrict__ srcB,
                                                   const float* __restrict__ bias,
                                                   float* __restrict__ out) {
    __shared__ __align__(16) u16 buf[4 * 64];
    int b, wl;
    swz_bucket(blockIdx.x, threadIdx.x, b, wl);
    const int wid = b * NN + wl;                    // bucket = b*NN+nd
    const int lane = threadIdx.x & 63;
    u16* wbuf = &buf[(threadIdx.x >> 6) * 64];
    const int total = merge_lists(ctr, srcB, BM, BN, wid, lane, wbuf);

    const bf16* base = x_edge + (size_t)b * MM * CC;  // same XCD pair wrote this slice
    const int g = lane >> 4;
    const int c16 = lane & 15;
    float s[8];
#pragma unroll
    for (int k = 0; k < 8; ++k) s[k] = 0.f;
    int i = 0;
    for (; i + 4 <= total; i += 4) {
        const int idx = wbuf[i + g];
        const uint4 pk = *(const uint4*)(base + (size_t)idx * CC + c16 * 8);
        acc8(pk, s);
    }
    if (i < total && g < total - i) {
        const int idx = wbuf[i + g];
        const uint4 pk = *(const uint4*)(base + (size_t)idx * CC + c16 * 8);
        acc8(pk, s);
    }
#pragma unroll
    for (int k = 0; k < 8; ++k) {
        s[k] += __shfl_xor(s[k], 16, 64);
        s[k] += __shfl_xor(s[k], 32, 64);
    }
    const float w = total ? 1.0f / (float)total : 0.f;
    if (g < 2) {                        // 32 lanes store 16B each (512B/wave)
        const float4 bv = *(const float4*)&bias[c16 * 8 + g * 4];
        f32x4 o;
        if (g == 0) {
            o.x = s[0] * w + bv.x; o.y = s[1] * w + bv.y;
            o.z = s[2] * w + bv.z; o.w = s[3] * w + bv.w;
        } else {
            o.x = s[4] * w + bv.x; o.y = s[5] * w + bv.y;
            o.z = s[6] * w + bv.z; o.w = s[7] * w + bv.w;
        }
        __builtin_nontemporal_store(o, (f32x4*)&out[(size_t)wid * CC + c16 * 8 + g * 4]);
    }
}

extern "C" void kernel_launch(void* const* d_in, const int* in_sizes, int n_in,
                              void* d_out, int out_size, void* d_ws, size_t ws_size,
                              hipStream_t stream) {
    const float* x = (const float*)d_in[0];
    const int* H = (const int*)d_in[1];
    const float* theta = (const float*)d_in[2];
    const float* bias = (const float*)d_in[3];
    float* out = (float*)d_out;

    // workspace (~43.5 MB): xt(bf16) | x_edge(bf16) | ctr(8 copies) | srcA | srcB
    bf16* xt = (bf16*)d_ws;                                   // 10.24 MB
    bf16* x_edge = xt + (size_t)BB * NN * CC;                 // 10.24 MB
    int* ctr = (int*)(x_edge + (size_t)BB * MM * CC);         // 2.56 MB
    u16* srcA = (u16*)(ctr + NCOPY * (BM + BN));              // 10.24 MB
    u16* srcB = srcA + (size_t)NCOPY * BM * CAPX;             // 10.24 MB

    hipMemsetAsync(ctr, 0, (size_t)NCOPY * (BM + BN) * sizeof(int), stream);

    build_gemm_k<<<3750, 256, 0, stream>>>(H, ctr, srcA, srcB, x, theta, xt);
    phase1_pull<<<BM / 4, 256, 0, stream>>>(xt, ctr, srcA, x_edge);
    phase2_pull<<<BN / 4, 256, 0, stream>>>(x_edge, ctr, srcB, bias, out);
}

// Round 4
// 179.677 us; speedup vs baseline: 1.1027x; 1.0266x over previous
//
#include <hip/hip_runtime.h>
#include <hip/hip_bf16.h>

// HyConv round 11: pay cross-XCD dirty-line latency ONCE and locally.
//  (a) phase1 additionally compacts the 8 B-side copy-lists into a flat 64-entry
//      record (flatB + cntB) written with batch-affinity -> dirty in the CONSUMER
//      XCD's L2; phase2's merge becomes 1 local cnt read + one 128B local read.
//  (b) ctr and fragment loads issued in parallel (fragments read unconditionally for
//      lane<8; garbage harmless) -> one remote latency instead of two serialized.
//  (c) build: 2 edges/thread (int2 H loads, 4 independent atomic chains per thread),
//      1250 build blocks; gemm/build split on bit 3 of blockIdx so both classes see
//      uniform XCD residues (grid 2512); per-copy load unchanged (Poisson(2), CAPX 16).
// memset(ctr) -> build_gemm -> phase1_pull(+B compact) -> phase2_pull

#define BB 4
#define NN 10000
#define MM 10000
#define EE 160000
#define CC 128
#define BM (BB * MM)   // 40000 hyperedge buckets
#define BN (BB * NN)   // 40000 node buckets
#define NCOPY 8
#define CAPX 16        // per-copy bucket capacity; per-copy deg ~ Poisson(2), P[>=17]~5e-11

typedef unsigned short u16;
using bf16 = __hip_bfloat16;
using bf162 = __hip_bfloat162;
typedef unsigned u32x4 __attribute__((ext_vector_type(4)));
typedef float f32x4 __attribute__((ext_vector_type(4)));

// ---------------- fused: gemm ((bi>>3)&1==0) || build ((bi>>3)&1==1) ----------------
// grid = 2512: 1250 gemm blocks (32 rows each), 1250 build blocks (2 edges/thread).
__global__ __launch_bounds__(256) void build_gemm_k(const int* __restrict__ H,
                                                    int* __restrict__ ctr,
                                                    u16* __restrict__ srcA,
                                                    u16* __restrict__ srcB,
                                                    const float* __restrict__ x,
                                                    const float* __restrict__ theta,
                                                    bf16* __restrict__ xt) {
    __shared__ float sTh[64 * 128];  // 32 KB
    __shared__ float sX[32 * 128];   // 16 KB
    const int bi = blockIdx.x;
    const int idx = (bi >> 4) * 8 + (bi & 7);  // index within class, XCD-uniform

    if ((bi >> 3) & 1) {
        // ---- build: 2 edges per thread, XCD-local copy = bi & 7 ----
        if (idx >= 1250) return;
        const int gidx = idx * 256 + threadIdx.x;    // 0..319,999
        const int g0 = gidx * 2;                     // even edge id, pair in same batch
        const int cp = bi & 7;
        const int b = g0 / EE, e = g0 - b * EE;
        const int2 nd2 = *(const int2*)&H[b * 2 * EE + e];
        const int2 he2 = *(const int2*)&H[b * 2 * EE + EE + e];
        {
            const int bktA = b * MM + he2.x;
            const int s = atomicAdd(&ctr[cp * (BM + BN) + bktA], 1);
            if (s < CAPX) srcA[((size_t)cp * BM + bktA) * CAPX + s] = (u16)nd2.x;
            const int bktB = b * NN + nd2.x;
            const int q = atomicAdd(&ctr[cp * (BM + BN) + BM + bktB], 1);
            if (q < CAPX) srcB[((size_t)cp * BN + bktB) * CAPX + q] = (u16)he2.x;
        }
        {
            const int bktA = b * MM + he2.y;
            const int s = atomicAdd(&ctr[cp * (BM + BN) + bktA], 1);
            if (s < CAPX) srcA[((size_t)cp * BM + bktA) * CAPX + s] = (u16)nd2.y;
            const int bktB = b * NN + nd2.y;
            const int q = atomicAdd(&ctr[cp * (BM + BN) + BM + bktB], 1);
            if (q < CAPX) srcB[((size_t)cp * BN + bktB) * CAPX + q] = (u16)he2.y;
        }
        return;
    }

    // ---- gemm: 32 rows x 128 cols per block; thread = 8 rows x 2 cols ----
    if (idx >= 1250) return;
    const int tid = threadIdx.x;
    const int row0 = idx * 32;  // rows 0..39968
    {
        const float4* src = (const float4*)&x[row0 * 128];  // 1024 float4
        float4* dst = (float4*)sX;
#pragma unroll
        for (int i = 0; i < 4; ++i) dst[tid + 256 * i] = src[tid + 256 * i];
    }
    const int cg2 = (tid & 63) * 2;  // column pair base (0..126)
    const int rg = tid >> 6;         // row group 0..3
    float ax[8], ay[8];
#pragma unroll
    for (int r = 0; r < 8; ++r) { ax[r] = 0.f; ay[r] = 0.f; }

    for (int half = 0; half < 2; ++half) {
        __syncthreads();
        {
            const float4* src = (const float4*)&theta[half * 64 * 128];
            float4* dst = (float4*)sTh;
#pragma unroll
            for (int i = 0; i < 8; ++i) dst[tid + 256 * i] = src[tid + 256 * i];
        }
        __syncthreads();
#pragma unroll
        for (int k4 = 0; k4 < 16; ++k4) {
            const int kk = 4 * k4;
            const float2 t0 = *(const float2*)&sTh[(kk + 0) * 128 + cg2];
            const float2 t1 = *(const float2*)&sTh[(kk + 1) * 128 + cg2];
            const float2 t2 = *(const float2*)&sTh[(kk + 2) * 128 + cg2];
            const float2 t3 = *(const float2*)&sTh[(kk + 3) * 128 + cg2];
#pragma unroll
            for (int r = 0; r < 8; ++r) {
                const float4 xv =
                    *(const float4*)&sX[(rg * 8 + r) * 128 + half * 64 + kk];
                ax[r] = fmaf(xv.x, t0.x, ax[r]); ay[r] = fmaf(xv.x, t0.y, ay[r]);
                ax[r] = fmaf(xv.y, t1.x, ax[r]); ay[r] = fmaf(xv.y, t1.y, ay[r]);
                ax[r] = fmaf(xv.z, t2.x, ax[r]); ay[r] = fmaf(xv.z, t2.y, ay[r]);
                ax[r] = fmaf(xv.w, t3.x, ax[r]); ay[r] = fmaf(xv.w, t3.y, ay[r]);
            }
        }
    }
#pragma unroll
    for (int r = 0; r < 8; ++r) {
        bf162 h;
        h.x = __float2bfloat16(ax[r]);
        h.y = __float2bfloat16(ay[r]);
        *(bf162*)&xt[(size_t)(row0 + rg * 8 + r) * 128 + cg2] = h;
    }
}

// ---------------- bf16-pair helpers ----------------
__device__ __forceinline__ float blo(unsigned w) { return __uint_as_float(w << 16); }
__device__ __forceinline__ float bhi(unsigned w) { return __uint_as_float(w & 0xffff0000u); }
__device__ __forceinline__ unsigned pk2(float a, float b) {
    bf162 h;
    h.x = __float2bfloat16(a);
    h.y = __float2bfloat16(b);
    return *(unsigned*)&h;
}

// accumulate 8 channels from a 16B chunk of one row
__device__ __forceinline__ void acc8(const uint4 pk, float* s) {
    s[0] += blo(pk.x); s[1] += bhi(pk.x);
    s[2] += blo(pk.y); s[3] += bhi(pk.y);
    s[4] += blo(pk.z); s[5] += bhi(pk.z);
    s[6] += blo(pk.w); s[7] += bhi(pk.w);
}

// XCD batch-affinity swizzle: default dispatch is round-robin blk->XCD (blk&7).
// Map batch b to XCD pair {2b,2b+1}; jj = block-within-batch (0..2499), bijective.
__device__ __forceinline__ void swz_bucket(int blk, int tid, int& b, int& wid_local4) {
    const int xcd = blk & 7;
    b = xcd >> 1;                                   // batch 0..3
    const int jj = ((blk >> 3) << 1) | (xcd & 1);   // 0..2499
    wid_local4 = jj * 4 + (tid >> 6);               // bucket within batch
}

// ---------------- phase1: x_edge[bkt] = mean over incident nodes of xt --------------
// Also compacts the 8 B-side copy lists for node bucket (b, wl) into flatB/cntB —
// written with batch affinity so phase2's reads are XCD-local.
__global__ __launch_bounds__(256) void phase1_pull(const bf16* __restrict__ xt,
                                                   const int* __restrict__ ctr,
                                                   const u16* __restrict__ srcA,
                                                   const u16* __restrict__ srcB,
                                                   u16* __restrict__ flatB,
                                                   int* __restrict__ cntB,
                                                   bf16* __restrict__ x_edge) {
    __shared__ __align__(16) u16 bufA[4 * 64];
    __shared__ __align__(16) u16 bufB[4 * 64];
    int b, wl;
    swz_bucket(blockIdx.x, threadIdx.x, b, wl);
    const int widA = b * MM + wl;                   // hyperedge bucket
    const int widB = b * NN + wl;                   // node bucket (same local index)
    const int lane = threadIdx.x & 63;
    const int w4 = threadIdx.x >> 6;
    u16* wbufA = &bufA[w4 * 64];
    u16* wbufB = &bufB[w4 * 64];

    // ---- issue ALL remote loads up-front: frags unconditionally (garbage harmless),
    //      ctr in parallel — one exposed remote latency instead of two.
    int cA = 0, cB = 0;
    uint4 a0, a1, b0, b1;
    if (lane < NCOPY) {
        const u16* la = srcA + ((size_t)lane * BM + widA) * CAPX;
        const u16* lb = srcB + ((size_t)lane * BN + widB) * CAPX;
        a0 = *(const uint4*)la; a1 = *(const uint4*)(la + 8);
        b0 = *(const uint4*)lb; b1 = *(const uint4*)(lb + 8);
        cA = ctr[lane * (BM + BN) + widA];       cA = cA > CAPX ? CAPX : cA;
        cB = ctr[lane * (BM + BN) + BM + widB];  cB = cB > CAPX ? CAPX : cB;
    }
    int pA = cA, pB = cB;  // inclusive prefixes over lanes 0..7
#pragma unroll
    for (int d = 1; d < 8; d <<= 1) {
        const int oA = __shfl_up(pA, d, 64);
        const int oB = __shfl_up(pB, d, 64);
        if (lane >= d) { pA += oA; pB += oB; }
    }
    const int baseA = pA - cA, baseB = pB - cB;
    int totA = __shfl(pA, 7, 64); totA = totA > 64 ? 64 : totA;
    int totB = __shfl(pB, 7, 64); totB = totB > 64 ? 64 : totB;
    if (lane < NCOPY) {
        const unsigned wa[8] = {a0.x, a0.y, a0.z, a0.w, a1.x, a1.y, a1.z, a1.w};
        const unsigned wb[8] = {b0.x, b0.y, b0.z, b0.w, b1.x, b1.y, b1.z, b1.w};
#pragma unroll
        for (int j = 0; j < CAPX; ++j) {
            const u16 va = (u16)((j & 1) ? (wa[j >> 1] >> 16) : (wa[j >> 1] & 0xffffu));
            const u16 vb = (u16)((j & 1) ? (wb[j >> 1] >> 16) : (wb[j >> 1] & 0xffffu));
            const int pa = baseA + j, pb = baseB + j;
            if (j < cA && pa < 64) wbufA[pa] = va;
            if (j < cB && pb < 64) wbufB[pb] = vb;
        }
    }
    __syncthreads();  // publish both LDS lists

    // ---- publish flat B record (128B, batch-affine -> consumer-local dirty) ----
    if (lane < 8)
        *(u32x4*)&flatB[(size_t)widB * 64 + lane * 8] = *(const u32x4*)&wbufB[lane * 8];
    if (lane == 0) cntB[widB] = totB;

    // ---- gather A: lane reads uint4 (8 channels); 64 lanes cover 4 rows/load ----
    const bf16* base = xt + (size_t)b * NN * CC;
    const int g = lane >> 4;     // row-group 0..3
    const int c16 = lane & 15;   // 16B chunk -> channels c16*8 .. +8
    float s[8];
#pragma unroll
    for (int k = 0; k < 8; ++k) s[k] = 0.f;
    int i = 0;
    for (; i + 4 <= totA; i += 4) {
        const int idx = wbufA[i + g];
        const uint4 pk = *(const uint4*)(base + (size_t)idx * CC + c16 * 8);
        acc8(pk, s);
    }
    if (i < totA && g < totA - i) {
        const int idx = wbufA[i + g];
        const uint4 pk = *(const uint4*)(base + (size_t)idx * CC + c16 * 8);
        acc8(pk, s);
    }
#pragma unroll
    for (int k = 0; k < 8; ++k) {
        s[k] += __shfl_xor(s[k], 16, 64);
        s[k] += __shfl_xor(s[k], 32, 64);
    }
    const float w = totA ? 1.0f / (float)totA : 0.f;
    if (g == 0) {
        u32x4 o;
        o.x = pk2(s[0] * w, s[1] * w);
        o.y = pk2(s[2] * w, s[3] * w);
        o.z = pk2(s[4] * w, s[5] * w);
        o.w = pk2(s[6] * w, s[7] * w);
        __builtin_nontemporal_store(o, (u32x4*)&x_edge[(size_t)widA * CC + c16 * 8]);
    }
}

// ---------------- phase2: out[bkt] = mean over incident hyperedges + bias -----------
// Merge is now: one local cnt read + one local 128B flat-record read.
__global__ __launch_bounds__(256) void phase2_pull(const bf16* __restrict__ x_edge,
                                                   const u16* __restrict__ flatB,
                                                   const int* __restrict__ cntB,
                                                   const float* __restrict__ bias,
                                                   float* __restrict__ out) {
    __shared__ __align__(16) u16 buf[4 * 64];
    int b, wl;
    swz_bucket(blockIdx.x, threadIdx.x, b, wl);
    const int wid = b * NN + wl;
    const int lane = threadIdx.x & 63;
    u16* wbuf = &buf[(threadIdx.x >> 6) * 64];
    const int t0 = cntB[wid];  // broadcast (same line, local-dirty L2 hit)
    if (lane < 8)
        *(u32x4*)&wbuf[lane * 8] = *(const u32x4*)&flatB[(size_t)wid * 64 + lane * 8];
    __syncthreads();
    const int total = t0 > 64 ? 64 : t0;

    const bf16* base = x_edge + (size_t)b * MM * CC;  // same XCD pair wrote this slice
    const int g = lane >> 4;
    const int c16 = lane & 15;
    float s[8];
#pragma unroll
    for (int k = 0; k < 8; ++k) s[k] = 0.f;
    int i = 0;
    for (; i + 4 <= total; i += 4) {
        const int idx = wbuf[i + g];
        const uint4 pk = *(const uint4*)(base + (size_t)idx * CC + c16 * 8);
        acc8(pk, s);
    }
    if (i < total && g < total - i) {
        const int idx = wbuf[i + g];
        const uint4 pk = *(const uint4*)(base + (size_t)idx * CC + c16 * 8);
        acc8(pk, s);
    }
#pragma unroll
    for (int k = 0; k < 8; ++k) {
        s[k] += __shfl_xor(s[k], 16, 64);
        s[k] += __shfl_xor(s[k], 32, 64);
    }
    const float w = total ? 1.0f / (float)total : 0.f;
    if (g < 2) {
        const float4 bv = *(const float4*)&bias[c16 * 8 + g * 4];
        f32x4 o;
        if (g == 0) {
            o.x = s[0] * w + bv.x; o.y = s[1] * w + bv.y;
            o.z = s[2] * w + bv.z; o.w = s[3] * w + bv.w;
        } else {
            o.x = s[4] * w + bv.x; o.y = s[5] * w + bv.y;
            o.z = s[6] * w + bv.z; o.w = s[7] * w + bv.w;
        }
        __builtin_nontemporal_store(o, (f32x4*)&out[(size_t)wid * CC + c16 * 8 + g * 4]);
    }
}

extern "C" void kernel_launch(void* const* d_in, const int* in_sizes, int n_in,
                              void* d_out, int out_size, void* d_ws, size_t ws_size,
                              hipStream_t stream) {
    const float* x = (const float*)d_in[0];
    const int* H = (const int*)d_in[1];
    const float* theta = (const float*)d_in[2];
    const float* bias = (const float*)d_in[3];
    float* out = (float*)d_out;

    // workspace (~48.8 MB): xt | x_edge | ctr | srcA | srcB | flatB | cntB
    bf16* xt = (bf16*)d_ws;                                   // 10.24 MB
    bf16* x_edge = xt + (size_t)BB * NN * CC;                 // 10.24 MB
    int* ctr = (int*)(x_edge + (size_t)BB * MM * CC);         // 2.56 MB
    u16* srcA = (u16*)(ctr + NCOPY * (BM + BN));              // 10.24 MB
    u16* srcB = srcA + (size_t)NCOPY * BM * CAPX;             // 10.24 MB
    u16* flatB = srcB + (size_t)NCOPY * BN * CAPX;            // 5.12 MB
    int* cntB = (int*)(flatB + (size_t)BN * 64);              // 0.16 MB

    hipMemsetAsync(ctr, 0, (size_t)NCOPY * (BM + BN) * sizeof(int), stream);

    build_gemm_k<<<2512, 256, 0, stream>>>(H, ctr, srcA, srcB, x, theta, xt);
    phase1_pull<<<BM / 4, 256, 0, stream>>>(xt, ctr, srcA, srcB, flatB, cntB, x_edge);
    phase2_pull<<<BN / 4, 256, 0, stream>>>(x_edge, flatB, cntB, bias, out);
}